// Round 6
// baseline (875.554 us; speedup 1.0000x reference)
//
#include <hip/hip_runtime.h>

#define TAILB 12.0f

typedef __attribute__((ext_vector_type(2))) float f32x2;

static __device__ __forceinline__ f32x2 fma2(f32x2 a, f32x2 b, f32x2 c) {
    return __builtin_elementwise_fma(a, b, c);   // -> v_pk_fma_f32
}
static __device__ __forceinline__ f32x2 max2(f32x2 a, f32x2 b) {
    return __builtin_elementwise_max(a, b);      // -> v_pk_max_f32
}

__device__ __forceinline__ float softplus_f(float z) {
    return (z > 15.f) ? z : log1pf(__expf(z));
}

// ---------------- prep: repack weights ----------------
// ws: W2P @0       65536 dw (256 KB): [slab=(l*2+nh)*4+w][kc 0..31][kk 0..3][nloc 0..15]
//                  n = 64nh+16w+nloc, k = 4kc+kk  (n-consecutive for pk pairing)
//     W3P @262144  24576 dw (96 KB):  [slab][nc 0..15][nn 0..3][ploc 0..11]
//                  p = 12w+ploc, n = 64nh+4nc+nn   (p-consecutive for pk pairing)
//     W1S @360448  2048 dw (8 KB):    [l][c 0..3][k]  c=0..2 -> W1[l][k][c], c=3 -> b1[l][k]
__global__ __launch_bounds__(256)
void prep_v6(const float* __restrict__ W1, const float* __restrict__ b1,
             const float* __restrict__ W2, const float* __restrict__ W3,
             float* __restrict__ W2P, float* __restrict__ W3P, float* __restrict__ W1S)
{
    int id = blockIdx.x * 256 + threadIdx.x;
    if (id < 65536) {
        int slab = id >> 11, within = id & 2047;
        int kc = within >> 6, i = within & 63;
        int kk = i >> 4, nloc = i & 15;
        int l = slab >> 3, nh = (slab >> 2) & 1, w = slab & 3;
        int n = 64 * nh + 16 * w + nloc;
        int k = 4 * kc + kk;
        W2P[id] = W2[l * 16384 + n * 128 + k];
    } else if (id < 90112) {
        int t = id - 65536;
        int slab = t / 768, within = t % 768;
        int nc = within / 48, i = within % 48;
        int nn = i / 12, ploc = i % 12;
        int l = slab >> 3, nh = (slab >> 2) & 1, w = slab & 3;
        int p = 12 * w + ploc;
        int n = 64 * nh + 4 * nc + nn;
        W3P[t] = (p < 46) ? W3[l * 5888 + p * 128 + n] : 0.f;
    } else if (id < 92160) {
        int t = id - 90112;
        int l = t >> 9, r = t & 511;
        int c = r >> 7, k = r & 127;
        W1S[t] = (c < 3) ? W1[l * 384 + k * 3 + c] : b1[l * 128 + k];
    }
}

// 128 samples/block (lane ln owns samples ln and ln+64), 4 waves.
// h1 lives in registers (16-k chunks): each h1[s][k] is only consumed by lane s,
// so LDS staging bought nothing but 16 barriers/layer. h2 half staged in LDS.
// Weights pk-packed; accumulators are f32x2 pairs over n/p with activation
// splatted -> v_pk_fma_f32, per-accumulator k-order unchanged (bit-identical).
__global__ __launch_bounds__(256, 3)
void rqs_v6(const float* __restrict__ inp, const float* __restrict__ cond,
            const float* __restrict__ W2P, const float* __restrict__ W3P,
            const float* __restrict__ W1S,
            const float* __restrict__ b2, const float* __restrict__ b3,
            float* __restrict__ out, int B)
{
    __shared__ __align__(16) float h2buf[128 * 64];   // n-half [s][nn] swizzled; pbuf overlays
    __shared__ float xbuf[128][5];                    // stride 5: gcd(5,32)=1, conflict-free
    __shared__ float ladb[2][128];
    __shared__ float ldacc[128];

    const int tid  = threadIdx.x;
    const int w    = tid >> 6;
    const int ln   = tid & 63;
    const int base = blockIdx.x * 128;
    float* pbuf = h2buf;                              // overlay [48][129]

    if (tid < 128) {
        float4 xi = reinterpret_cast<const float4*>(inp)[base + tid];
        xbuf[tid][0] = xi.x; xbuf[tid][1] = xi.y;
        xbuf[tid][2] = xi.z; xbuf[tid][3] = xi.w;
        xbuf[tid][4] = cond[base + tid];
        ldacc[tid] = 0.f;
    }
    __syncthreads();

    #pragma unroll 1
    for (int l = 0; l < 4; ++l) {
        int mi0, mi1, ii0, ii1;
        switch (l) {
            case 0:  mi0 = 0; mi1 = 2; ii0 = 1; ii1 = 3; break;
            case 1:  mi0 = 1; mi1 = 3; ii0 = 0; ii1 = 2; break;
            case 2:  mi0 = 0; mi1 = 1; ii0 = 2; ii1 = 3; break;
            default: mi0 = 2; mi1 = 3; ii0 = 0; ii1 = 1; break;
        }

        // GEMM3 accumulators: p-pairs {12w+2q, 12w+2q+1}, per sample
        f32x2 pacc_a[6], pacc_b[6];
        {
            int pb = __builtin_amdgcn_readfirstlane(l * 46 + 12 * w);
            #pragma unroll
            for (int q = 0; q < 6; ++q) {
                int p0 = 12 * w + 2 * q;
                float v0 = (p0 < 46)     ? b3[pb + 2 * q]     : 0.f;
                float v1 = (p0 + 1 < 46) ? b3[pb + 2 * q + 1] : 0.f;
                f32x2 v = {v0, v1};
                pacc_a[q] = v; pacc_b[q] = v;
            }
        }

        float m0a = xbuf[ln][mi0],      m1a = xbuf[ln][mi1],      ca = xbuf[ln][4];
        float m0b = xbuf[ln + 64][mi0], m1b = xbuf[ln + 64][mi1], cb = xbuf[ln + 64][4];
        f32x2 m0as = {m0a, m0a}, m1as = {m1a, m1a}, cas = {ca, ca};
        f32x2 m0bs = {m0b, m0b}, m1bs = {m1b, m1b}, cbs = {cb, cb};
        const float* w1l = W1S + l * 512;

        #pragma unroll 1
        for (int nh = 0; nh < 2; ++nh) {
            // GEMM2 accumulators: n-pairs {64nh+16w+2q, +2q+1}, per sample
            f32x2 aacc[8], bacc[8];
            {
                int nb = __builtin_amdgcn_readfirstlane(l * 128 + 64 * nh + 16 * w);
                #pragma unroll
                for (int q = 0; q < 8; ++q) {
                    f32x2 v = {b2[nb + 2 * q], b2[nb + 2 * q + 1]};
                    aacc[q] = v; bacc[q] = v;
                }
            }
            const float* w2s = W2P +
                __builtin_amdgcn_readfirstlane(((l * 2 + nh) * 4 + w) * 2048);

            #pragma unroll 1
            for (int ke = 0; ke < 8; ++ke) {       // 16 k per iteration
                // ---- h1 chunk in regs (k-pairs), both samples ----
                f32x2 ha[8], hb[8];
                #pragma unroll
                for (int g = 0; g < 4; ++g) {
                    int kb = 16 * ke + 4 * g;
                    float4 wx = *reinterpret_cast<const float4*>(w1l + kb);
                    float4 wy = *reinterpret_cast<const float4*>(w1l + 128 + kb);
                    float4 wz = *reinterpret_cast<const float4*>(w1l + 256 + kb);
                    float4 wv = *reinterpret_cast<const float4*>(w1l + 384 + kb);
                    f32x2 zero = {0.f, 0.f};
                    f32x2 x01 = {wx.x, wx.y}, x23 = {wx.z, wx.w};
                    f32x2 y01 = {wy.x, wy.y}, y23 = {wy.z, wy.w};
                    f32x2 z01 = {wz.x, wz.y}, z23 = {wz.z, wz.w};
                    f32x2 v01 = {wv.x, wv.y}, v23 = {wv.z, wv.w};
                    ha[2*g]   = max2(fma2(x01, m0as, fma2(y01, m1as, fma2(z01, cas, v01))), zero);
                    ha[2*g+1] = max2(fma2(x23, m0as, fma2(y23, m1as, fma2(z23, cas, v23))), zero);
                    hb[2*g]   = max2(fma2(x01, m0bs, fma2(y01, m1bs, fma2(z01, cbs, v01))), zero);
                    hb[2*g+1] = max2(fma2(x23, m0bs, fma2(y23, m1bs, fma2(z23, cbs, v23))), zero);
                }
                // ---- GEMM2: 4 chunks of (4k x 16n) ----
                #pragma unroll
                for (int c = 0; c < 4; ++c) {
                    const float4* wq = reinterpret_cast<const float4*>(
                        w2s + (ke * 4 + c) * 64);
                    #pragma unroll
                    for (int kk = 0; kk < 4; ++kk) {
                        int kloc = 4 * c + kk;
                        float av = (kloc & 1) ? ha[kloc >> 1].y : ha[kloc >> 1].x;
                        float bv = (kloc & 1) ? hb[kloc >> 1].y : hb[kloc >> 1].x;
                        f32x2 avs = {av, av}, bvs = {bv, bv};
                        float4 u0 = wq[kk * 4 + 0];
                        float4 u1 = wq[kk * 4 + 1];
                        float4 u2 = wq[kk * 4 + 2];
                        float4 u3 = wq[kk * 4 + 3];
                        f32x2 p0 = {u0.x, u0.y}, p1 = {u0.z, u0.w};
                        f32x2 p2 = {u1.x, u1.y}, p3 = {u1.z, u1.w};
                        f32x2 p4 = {u2.x, u2.y}, p5 = {u2.z, u2.w};
                        f32x2 p6 = {u3.x, u3.y}, p7 = {u3.z, u3.w};
                        aacc[0] = fma2(p0, avs, aacc[0]);
                        aacc[1] = fma2(p1, avs, aacc[1]);
                        aacc[2] = fma2(p2, avs, aacc[2]);
                        aacc[3] = fma2(p3, avs, aacc[3]);
                        aacc[4] = fma2(p4, avs, aacc[4]);
                        aacc[5] = fma2(p5, avs, aacc[5]);
                        aacc[6] = fma2(p6, avs, aacc[6]);
                        aacc[7] = fma2(p7, avs, aacc[7]);
                        bacc[0] = fma2(p0, bvs, bacc[0]);
                        bacc[1] = fma2(p1, bvs, bacc[1]);
                        bacc[2] = fma2(p2, bvs, bacc[2]);
                        bacc[3] = fma2(p3, bvs, bacc[3]);
                        bacc[4] = fma2(p4, bvs, bacc[4]);
                        bacc[5] = fma2(p5, bvs, bacc[5]);
                        bacc[6] = fma2(p6, bvs, bacc[6]);
                        bacc[7] = fma2(p7, bvs, bacc[7]);
                    }
                }
            } // ke

            __syncthreads();   // h2buf WAR (prev nh GEMM3 / prev layer pbuf reads done)
            // ---- epilogue: relu, write n-half ----
            {
                int swk = ln & 15;
                #pragma unroll
                for (int gi = 0; gi < 4; ++gi) {
                    int g = 4 * w + gi;
                    float4 v0, v1;
                    v0.x = fmaxf(aacc[2*gi].x,   0.f);
                    v0.y = fmaxf(aacc[2*gi].y,   0.f);
                    v0.z = fmaxf(aacc[2*gi+1].x, 0.f);
                    v0.w = fmaxf(aacc[2*gi+1].y, 0.f);
                    v1.x = fmaxf(bacc[2*gi].x,   0.f);
                    v1.y = fmaxf(bacc[2*gi].y,   0.f);
                    v1.z = fmaxf(bacc[2*gi+1].x, 0.f);
                    v1.w = fmaxf(bacc[2*gi+1].y, 0.f);
                    *reinterpret_cast<float4*>(&h2buf[ln * 64 + ((g ^ swk) << 2)]) = v0;
                    *reinterpret_cast<float4*>(&h2buf[(ln + 64) * 64 + ((g ^ swk) << 2)]) = v1;
                }
            }
            __syncthreads();

            // ---- GEMM3 over this n-half: 16 chunks of (4n x 12p) ----
            {
                const float* w3s = W3P +
                    __builtin_amdgcn_readfirstlane(((l * 2 + nh) * 4 + w) * 768);
                int swk = ln & 15;
                #pragma unroll 1
                for (int nc = 0; nc < 16; ++nc) {
                    float4 a4 = *reinterpret_cast<const float4*>(
                        &h2buf[ln * 64 + ((nc ^ swk) << 2)]);
                    float4 b4 = *reinterpret_cast<const float4*>(
                        &h2buf[(ln + 64) * 64 + ((nc ^ swk) << 2)]);
                    const float4* wq = reinterpret_cast<const float4*>(w3s + nc * 48);
                    float aval[4] = {a4.x, a4.y, a4.z, a4.w};
                    float bval[4] = {b4.x, b4.y, b4.z, b4.w};
                    #pragma unroll
                    for (int nn = 0; nn < 4; ++nn) {
                        float4 wA = wq[nn * 3 + 0];
                        float4 wB = wq[nn * 3 + 1];
                        float4 wC = wq[nn * 3 + 2];
                        f32x2 ans = {aval[nn], aval[nn]};
                        f32x2 bns = {bval[nn], bval[nn]};
                        f32x2 q0 = {wA.x, wA.y}, q1 = {wA.z, wA.w};
                        f32x2 q2 = {wB.x, wB.y}, q3 = {wB.z, wB.w};
                        f32x2 q4 = {wC.x, wC.y}, q5 = {wC.z, wC.w};
                        pacc_a[0] = fma2(q0, ans, pacc_a[0]);
                        pacc_a[1] = fma2(q1, ans, pacc_a[1]);
                        pacc_a[2] = fma2(q2, ans, pacc_a[2]);
                        pacc_a[3] = fma2(q3, ans, pacc_a[3]);
                        pacc_a[4] = fma2(q4, ans, pacc_a[4]);
                        pacc_a[5] = fma2(q5, ans, pacc_a[5]);
                        pacc_b[0] = fma2(q0, bns, pacc_b[0]);
                        pacc_b[1] = fma2(q1, bns, pacc_b[1]);
                        pacc_b[2] = fma2(q2, bns, pacc_b[2]);
                        pacc_b[3] = fma2(q3, bns, pacc_b[3]);
                        pacc_b[4] = fma2(q4, bns, pacc_b[4]);
                        pacc_b[5] = fma2(q5, bns, pacc_b[5]);
                    }
                }
            }
        } // nh

        __syncthreads();   // GEMM3 h2buf reads done -> pbuf overlay safe
        #pragma unroll
        for (int q = 0; q < 6; ++q) {
            int p0 = 12 * w + 2 * q;
            if (p0 < 46) {
                pbuf[p0 * 129 + ln]      = pacc_a[q].x;
                pbuf[p0 * 129 + ln + 64] = pacc_b[q].x;
            }
            if (p0 + 1 < 46) {
                pbuf[(p0 + 1) * 129 + ln]      = pacc_a[q].y;
                pbuf[(p0 + 1) * 129 + ln + 64] = pacc_b[q].y;
            }
        }
        __syncthreads();

        // ---- spline: thread (f = tid>>7, s = tid&127) ----
        {
            int f = tid >> 7, s = tid & 127;
            float pr[23];
            #pragma unroll
            for (int i = 0; i < 23; ++i) pr[i] = pbuf[(2 * i + f) * 129 + s];

            float xin = xbuf[s][f == 0 ? ii0 : ii1];

            float d[9];
            d[0] = 1.f; d[8] = 1.f;
            #pragma unroll
            for (int k = 1; k < 8; ++k) d[k] = 1e-6f + softplus_f(pr[16 + k - 1]);

            bool inside = (xin >= -TAILB) && (xin <= TAILB);
            float xc = fminf(fmaxf(xin, -TAILB), TAILB);

            float mw = pr[0], mh = pr[8];
            #pragma unroll
            for (int k = 1; k < 8; ++k) { mw = fmaxf(mw, pr[k]); mh = fmaxf(mh, pr[8 + k]); }
            float ew[8], eh[8], swm = 0.f, shm = 0.f;
            #pragma unroll
            for (int k = 0; k < 8; ++k) {
                ew[k] = __expf(pr[k] - mw);     swm += ew[k];
                eh[k] = __expf(pr[8 + k] - mh); shm += eh[k];
            }
            const float c1 = 1.f - 8e-6f;
            float isw = c1 / swm, ish = c1 / shm;

            float cum_w = 0.f, cum_h = 0.f;
            float cwk = -TAILB, chk = -TAILB;
            float s_cw = -TAILB, s_w = 2.f * TAILB, s_ch = -TAILB, s_h = 2.f * TAILB;
            float s_d0 = 1.f, s_d1 = d[1];
            #pragma unroll
            for (int k = 0; k < 8; ++k) {
                cum_w += fmaf(ew[k], isw, 1e-6f);
                cum_h += fmaf(eh[k], ish, 1e-6f);
                float cwn = (k == 7) ? TAILB : fmaf(2.f * TAILB, cum_w, -TAILB);
                float chn = (k == 7) ? TAILB : fmaf(2.f * TAILB, cum_h, -TAILB);
                bool ge = (xc >= cwk);
                s_cw = ge ? cwk : s_cw;  s_w = ge ? (cwn - cwk) : s_w;
                s_ch = ge ? chk : s_ch;  s_h = ge ? (chn - chk) : s_h;
                s_d0 = ge ? d[k] : s_d0; s_d1 = ge ? d[k + 1] : s_d1;
                cwk = cwn; chk = chn;
            }

            float th    = (xc - s_cw) / s_w;
            float delta = s_h / s_w;
            float omt   = 1.f - th;
            float tomt  = th * omt;
            float num   = s_h * fmaf(delta, th * th, s_d0 * tomt);
            float den   = fmaf(s_d0 + s_d1 - 2.f * delta, tomt, delta);
            float y     = s_ch + num / den;
            float dnum  = delta * delta * (s_d1 * th * th + 2.f * delta * tomt + s_d0 * omt * omt);
            float lad   = __logf(dnum) - 2.f * __logf(den);

            xbuf[s][f == 0 ? ii0 : ii1] = inside ? y : xin;
            ladb[f][s] = inside ? lad : 0.f;
        }
        __syncthreads();
        if (tid < 128) ldacc[tid] += ladb[0][tid] + ladb[1][tid];
        // next writes to ladb/xbuf/h2buf are all behind >=1 barrier
    } // l

    if (tid < 128) {
        float4 xo;
        xo.x = xbuf[tid][0]; xo.y = xbuf[tid][1];
        xo.z = xbuf[tid][2]; xo.w = xbuf[tid][3];
        reinterpret_cast<float4*>(out)[base + tid] = xo;
        out[(size_t)B * 4 + base + tid] = ldacc[tid];
    }
}

extern "C" void kernel_launch(void* const* d_in, const int* in_sizes, int n_in,
                              void* d_out, int out_size, void* d_ws, size_t ws_size,
                              hipStream_t stream) {
    const float* inp  = (const float*)d_in[0];
    const float* cond = (const float*)d_in[1];
    const float* W1   = (const float*)d_in[2];
    const float* b1   = (const float*)d_in[3];
    const float* W2   = (const float*)d_in[4];
    const float* b2   = (const float*)d_in[5];
    const float* W3   = (const float*)d_in[6];
    const float* b3   = (const float*)d_in[7];
    float* out = (float*)d_out;
    int B = in_sizes[0] / 4;

    float* W2P = (float*)d_ws;                       // 262144 B
    float* W3P = (float*)((char*)d_ws + 262144);     // 98304 B
    float* W1S = (float*)((char*)d_ws + 360448);     // 8192 B

    hipLaunchKernelGGL(prep_v6, dim3(360), dim3(256), 0, stream,
                       W1, b1, W2, W3, W2P, W3P, W1S);
    hipLaunchKernelGGL(rqs_v6, dim3(B / 128), dim3(256), 0, stream,
                       inp, cond, W2P, W3P, W1S, b2, b3, out, B);
}

// Round 7
// 584.404 us; speedup vs baseline: 1.4982x; 1.4982x over previous
//
#include <hip/hip_runtime.h>

#define TAILB 12.0f

__device__ __forceinline__ float softplus_f(float z) {
    return (z > 15.f) ? z : log1pf(__expf(z));
}

// ---------------- prep: repack weights ----------------
// ws: W2P @0       65536 dw (256 KB): [slab=(l*2+nh)*4+w][b 0..63][kk 0..1][nloc 0..15]
//                  n = 64nh+16w+nloc, k = 2b+kk   (32-dw batches for ping-pong)
//     W3P @262144  24576 dw (96 KB):  [slab][hb 0..31][nn 0..1][ploc 0..11]
//                  p = 12w+ploc, n = 64nh+2hb+nn  (24-dw half-batches)
//     W1S @360448  2048 dw (8 KB):    [l][c 0..3][k]  c<3 -> W1[l][k][c], c==3 -> b1[l][k]
__global__ __launch_bounds__(256)
void prep_v7(const float* __restrict__ W1, const float* __restrict__ b1,
             const float* __restrict__ W2, const float* __restrict__ W3,
             float* __restrict__ W2P, float* __restrict__ W3P, float* __restrict__ W1S)
{
    int id = blockIdx.x * 256 + threadIdx.x;
    if (id < 65536) {
        int slab = id >> 11, within = id & 2047;
        int b = within >> 5, i = within & 31;
        int kk = i >> 4, nloc = i & 15;
        int l = slab >> 3, nh = (slab >> 2) & 1, w = slab & 3;
        int n = 64 * nh + 16 * w + nloc;
        int k = 2 * b + kk;
        W2P[id] = W2[l * 16384 + n * 128 + k];
    } else if (id < 90112) {
        int t = id - 65536;
        int slab = t / 768, within = t % 768;
        int hb = within / 24, i = within % 24;
        int nn = i / 12, ploc = i % 12;
        int l = slab >> 3, nh = (slab >> 2) & 1, w = slab & 3;
        int p = 12 * w + ploc;
        int n = 64 * nh + 2 * hb + nn;
        W3P[t] = (p < 46) ? W3[l * 5888 + p * 128 + n] : 0.f;
    } else if (id < 92160) {
        int t = id - 90112;
        int l = t >> 9, r = t & 511;
        int c = r >> 7, k = r & 127;
        W1S[t] = (c < 3) ? W1[l * 384 + k * 3 + c] : b1[l * 128 + k];
    }
}

static __device__ __forceinline__ void fma16x2(const float4* u, float av, float bv,
                                               float* acc0, float* acc1) {
    #pragma unroll
    for (int jj = 0; jj < 4; ++jj) {
        float4 q = u[jj];
        acc0[4*jj+0] = fmaf(q.x, av, acc0[4*jj+0]);
        acc0[4*jj+1] = fmaf(q.y, av, acc0[4*jj+1]);
        acc0[4*jj+2] = fmaf(q.z, av, acc0[4*jj+2]);
        acc0[4*jj+3] = fmaf(q.w, av, acc0[4*jj+3]);
        acc1[4*jj+0] = fmaf(q.x, bv, acc1[4*jj+0]);
        acc1[4*jj+1] = fmaf(q.y, bv, acc1[4*jj+1]);
        acc1[4*jj+2] = fmaf(q.z, bv, acc1[4*jj+2]);
        acc1[4*jj+3] = fmaf(q.w, bv, acc1[4*jj+3]);
    }
}

static __device__ __forceinline__ void fma12x2(const float4* u, float av, float bv,
                                               float* p0, float* p1) {
    #pragma unroll
    for (int jj = 0; jj < 3; ++jj) {
        float4 q = u[jj];
        p0[4*jj+0] = fmaf(q.x, av, p0[4*jj+0]);
        p0[4*jj+1] = fmaf(q.y, av, p0[4*jj+1]);
        p0[4*jj+2] = fmaf(q.z, av, p0[4*jj+2]);
        p0[4*jj+3] = fmaf(q.w, av, p0[4*jj+3]);
        p1[4*jj+0] = fmaf(q.x, bv, p1[4*jj+0]);
        p1[4*jj+1] = fmaf(q.y, bv, p1[4*jj+1]);
        p1[4*jj+2] = fmaf(q.z, bv, p1[4*jj+2]);
        p1[4*jj+3] = fmaf(q.w, bv, p1[4*jj+3]);
    }
}

// 128 samples/block, 4 waves; lane ln owns samples ln, ln+64.
// sbuf (32 KB) time-multiplexes: h1 k-half -> h2 n-half -> pbuf (never co-live).
// Cooperative h1 stage (computed once, read by 4 waves). Weight stream is
// ping-pong double-buffered (8-f4 batches) so loads overlap the FMA blocks.
// Swizzle: quad group g stored at g^(s&15) on 64-dw rows (v6-measured 0 conflicts).
__global__ __launch_bounds__(256, 2)
void rqs_v7(const float* __restrict__ inp, const float* __restrict__ cond,
            const float* __restrict__ W2P, const float* __restrict__ W3P,
            const float* __restrict__ W1S,
            const float* __restrict__ b2, const float* __restrict__ b3,
            float* __restrict__ out, int B)
{
    __shared__ __align__(16) float sbuf[128 * 64];   // h1-half / h2-half / pbuf[48][129]
    __shared__ float xbuf[128][5];
    __shared__ float ladb[2][128];
    __shared__ float ldacc[128];

    const int tid  = threadIdx.x;
    const int w    = tid >> 6;
    const int ln   = tid & 63;
    const int base = blockIdx.x * 128;
    float* pbuf = sbuf;

    if (tid < 128) {
        float4 xi = reinterpret_cast<const float4*>(inp)[base + tid];
        xbuf[tid][0] = xi.x; xbuf[tid][1] = xi.y;
        xbuf[tid][2] = xi.z; xbuf[tid][3] = xi.w;
        xbuf[tid][4] = cond[base + tid];
        ldacc[tid] = 0.f;
    }
    __syncthreads();

    #pragma unroll 1
    for (int l = 0; l < 4; ++l) {
        int mi0, mi1, ii0, ii1;
        switch (l) {
            case 0:  mi0 = 0; mi1 = 2; ii0 = 1; ii1 = 3; break;
            case 1:  mi0 = 1; mi1 = 3; ii0 = 0; ii1 = 2; break;
            case 2:  mi0 = 0; mi1 = 1; ii0 = 2; ii1 = 3; break;
            default: mi0 = 2; mi1 = 3; ii0 = 0; ii1 = 1; break;
        }

        // GEMM3 accumulators (live across the layer): p = 12w + i
        float pacc0[12], pacc1[12];
        {
            int pb = __builtin_amdgcn_readfirstlane(l * 46 + 12 * w);
            #pragma unroll
            for (int i = 0; i < 12; ++i) {
                float bv = (12 * w + i < 46) ? b3[pb + i] : 0.f;
                pacc0[i] = bv; pacc1[i] = bv;
            }
        }

        #pragma unroll 1
        for (int nh = 0; nh < 2; ++nh) {
            // GEMM2 accumulators: n = 64nh + 16w + j
            float acc0[16], acc1[16];
            {
                int nb = __builtin_amdgcn_readfirstlane(l * 128 + 64 * nh + 16 * w);
                #pragma unroll
                for (int j = 0; j < 16; ++j) {
                    float bv = b2[nb + j];
                    acc0[j] = bv; acc1[j] = bv;
                }
            }

            #pragma unroll 1
            for (int kh = 0; kh < 2; ++kh) {
                __syncthreads();   // WAR: prior sbuf readers done
                // ---- h1 stage: thread (s=tid&127, sl=tid>>7) covers 32 k ----
                {
                    int s = tid & 127;
                    int sl = __builtin_amdgcn_readfirstlane(tid >> 7);
                    float m0 = xbuf[s][mi0], m1 = xbuf[s][mi1], cc = xbuf[s][4];
                    int swk = s & 15;
                    const float* w1l = W1S + l * 512;
                    #pragma unroll
                    for (int g = 0; g < 8; ++g) {
                        int qg = sl * 8 + g;               // quad group 0..15 in half
                        int k = kh * 64 + qg * 4;          // absolute k (x4 aligned)
                        float4 wx = *reinterpret_cast<const float4*>(w1l + k);
                        float4 wy = *reinterpret_cast<const float4*>(w1l + 128 + k);
                        float4 wz = *reinterpret_cast<const float4*>(w1l + 256 + k);
                        float4 wb = *reinterpret_cast<const float4*>(w1l + 384 + k);
                        float4 v;
                        v.x = fmaxf(fmaf(wx.x, m0, fmaf(wy.x, m1, fmaf(wz.x, cc, wb.x))), 0.f);
                        v.y = fmaxf(fmaf(wx.y, m0, fmaf(wy.y, m1, fmaf(wz.y, cc, wb.y))), 0.f);
                        v.z = fmaxf(fmaf(wx.z, m0, fmaf(wy.z, m1, fmaf(wz.z, cc, wb.z))), 0.f);
                        v.w = fmaxf(fmaf(wx.w, m0, fmaf(wy.w, m1, fmaf(wz.w, cc, wb.w))), 0.f);
                        *reinterpret_cast<float4*>(&sbuf[s * 64 + ((qg ^ swk) << 2)]) = v;
                    }
                }
                __syncthreads();

                // ---- GEMM2 over this k-half: 16 bi, ping-pong 8-f4 batches ----
                {
                    const float4* wq = reinterpret_cast<const float4*>(
                        W2P + __builtin_amdgcn_readfirstlane(
                            ((l * 2 + nh) * 4 + w) * 2048 + kh * 1024));
                    int swk = ln & 15;
                    float4 WA[8], WB[8];
                    #pragma unroll
                    for (int j = 0; j < 8; ++j) WA[j] = wq[j];   // batch 0
                    #pragma unroll 1
                    for (int bi = 0; bi < 16; ++bi) {
                        #pragma unroll
                        for (int j = 0; j < 8; ++j) WB[j] = wq[(2 * bi + 1) * 8 + j];
                        float4 a4 = *reinterpret_cast<const float4*>(
                            &sbuf[ln * 64 + ((bi ^ swk) << 2)]);
                        float4 b4 = *reinterpret_cast<const float4*>(
                            &sbuf[(ln + 64) * 64 + ((bi ^ swk) << 2)]);
                        fma16x2(&WA[0], a4.x, b4.x, acc0, acc1);   // k = 4bi
                        fma16x2(&WA[4], a4.y, b4.y, acc0, acc1);   // k = 4bi+1
                        #pragma unroll
                        for (int j = 0; j < 8; ++j) WA[j] = wq[(2 * bi + 2) * 8 + j];
                        fma16x2(&WB[0], a4.z, b4.z, acc0, acc1);   // k = 4bi+2
                        fma16x2(&WB[4], a4.w, b4.w, acc0, acc1);   // k = 4bi+3
                    }
                }
            } // kh

            __syncthreads();   // last h1 reads done -> h2 overwrite safe
            // ---- epilogue: relu, write h2 n-half ----
            {
                int swk = ln & 15;
                #pragma unroll
                for (int gi = 0; gi < 4; ++gi) {
                    int g = 4 * w + gi;
                    float4 v0, v1;
                    v0.x = fmaxf(acc0[4*gi+0], 0.f); v1.x = fmaxf(acc1[4*gi+0], 0.f);
                    v0.y = fmaxf(acc0[4*gi+1], 0.f); v1.y = fmaxf(acc1[4*gi+1], 0.f);
                    v0.z = fmaxf(acc0[4*gi+2], 0.f); v1.z = fmaxf(acc1[4*gi+2], 0.f);
                    v0.w = fmaxf(acc0[4*gi+3], 0.f); v1.w = fmaxf(acc1[4*gi+3], 0.f);
                    *reinterpret_cast<float4*>(&sbuf[ln * 64 + ((g ^ swk) << 2)]) = v0;
                    *reinterpret_cast<float4*>(&sbuf[(ln + 64) * 64 + ((g ^ swk) << 2)]) = v1;
                }
            }
            __syncthreads();

            // ---- GEMM3 over this n-half: 16 gi, ping-pong 6-f4 half-batches ----
            {
                const float* w3s = W3P + __builtin_amdgcn_readfirstlane(
                    ((l * 2 + nh) * 4 + w) * 768);
                int swk = ln & 15;
                float4 VA[6], VB[6];
                const float4* vq = reinterpret_cast<const float4*>(w3s);
                #pragma unroll
                for (int j = 0; j < 6; ++j) VA[j] = vq[j];   // hb 0
                #pragma unroll 1
                for (int gi = 0; gi < 16; ++gi) {
                    #pragma unroll
                    for (int j = 0; j < 6; ++j) VB[j] = vq[(2 * gi + 1) * 6 + j];
                    float4 a4 = *reinterpret_cast<const float4*>(
                        &sbuf[ln * 64 + ((gi ^ swk) << 2)]);
                    float4 b4 = *reinterpret_cast<const float4*>(
                        &sbuf[(ln + 64) * 64 + ((gi ^ swk) << 2)]);
                    fma12x2(&VA[0], a4.x, b4.x, pacc0, pacc1);  // n = 4gi
                    fma12x2(&VA[3], a4.y, b4.y, pacc0, pacc1);  // n = 4gi+1
                    #pragma unroll
                    for (int j = 0; j < 6; ++j) VA[j] = vq[(2 * gi + 2) * 6 + j];
                    fma12x2(&VB[0], a4.z, b4.z, pacc0, pacc1);  // n = 4gi+2
                    fma12x2(&VB[3], a4.w, b4.w, pacc0, pacc1);  // n = 4gi+3
                }
            }
        } // nh

        __syncthreads();   // GEMM3 reads done -> pbuf overlay safe
        #pragma unroll
        for (int i = 0; i < 12; ++i) {
            int p = 12 * w + i;
            if (p < 46) {
                pbuf[p * 129 + ln]      = pacc0[i];
                pbuf[p * 129 + ln + 64] = pacc1[i];
            }
        }
        __syncthreads();

        // ---- spline: thread (f = tid>>7, s = tid&127) ----
        {
            int f = tid >> 7, s = tid & 127;
            float pr[23];
            #pragma unroll
            for (int i = 0; i < 23; ++i) pr[i] = pbuf[(2 * i + f) * 129 + s];

            float xin = xbuf[s][f == 0 ? ii0 : ii1];

            float d[9];
            d[0] = 1.f; d[8] = 1.f;
            #pragma unroll
            for (int k = 1; k < 8; ++k) d[k] = 1e-6f + softplus_f(pr[16 + k - 1]);

            bool inside = (xin >= -TAILB) && (xin <= TAILB);
            float xc = fminf(fmaxf(xin, -TAILB), TAILB);

            float mw = pr[0], mh = pr[8];
            #pragma unroll
            for (int k = 1; k < 8; ++k) { mw = fmaxf(mw, pr[k]); mh = fmaxf(mh, pr[8 + k]); }
            float ew[8], eh[8], swm = 0.f, shm = 0.f;
            #pragma unroll
            for (int k = 0; k < 8; ++k) {
                ew[k] = __expf(pr[k] - mw);     swm += ew[k];
                eh[k] = __expf(pr[8 + k] - mh); shm += eh[k];
            }
            const float c1 = 1.f - 8e-6f;
            float isw = c1 / swm, ish = c1 / shm;

            float cum_w = 0.f, cum_h = 0.f;
            float cwk = -TAILB, chk = -TAILB;
            float s_cw = -TAILB, s_w = 2.f * TAILB, s_ch = -TAILB, s_h = 2.f * TAILB;
            float s_d0 = 1.f, s_d1 = d[1];
            #pragma unroll
            for (int k = 0; k < 8; ++k) {
                cum_w += fmaf(ew[k], isw, 1e-6f);
                cum_h += fmaf(eh[k], ish, 1e-6f);
                float cwn = (k == 7) ? TAILB : fmaf(2.f * TAILB, cum_w, -TAILB);
                float chn = (k == 7) ? TAILB : fmaf(2.f * TAILB, cum_h, -TAILB);
                bool ge = (xc >= cwk);
                s_cw = ge ? cwk : s_cw;  s_w = ge ? (cwn - cwk) : s_w;
                s_ch = ge ? chk : s_ch;  s_h = ge ? (chn - chk) : s_h;
                s_d0 = ge ? d[k] : s_d0; s_d1 = ge ? d[k + 1] : s_d1;
                cwk = cwn; chk = chn;
            }

            float th    = (xc - s_cw) / s_w;
            float delta = s_h / s_w;
            float omt   = 1.f - th;
            float tomt  = th * omt;
            float num   = s_h * fmaf(delta, th * th, s_d0 * tomt);
            float den   = fmaf(s_d0 + s_d1 - 2.f * delta, tomt, delta);
            float y     = s_ch + num / den;
            float dnum  = delta * delta * (s_d1 * th * th + 2.f * delta * tomt + s_d0 * omt * omt);
            float lad   = __logf(dnum) - 2.f * __logf(den);

            xbuf[s][f == 0 ? ii0 : ii1] = inside ? y : xin;
            ladb[f][s] = inside ? lad : 0.f;
        }
        __syncthreads();
        if (tid < 128) ldacc[tid] += ladb[0][tid] + ladb[1][tid];
        // next sbuf/xbuf/ladb writes are all behind >=1 barrier
    } // l

    if (tid < 128) {
        float4 xo;
        xo.x = xbuf[tid][0]; xo.y = xbuf[tid][1];
        xo.z = xbuf[tid][2]; xo.w = xbuf[tid][3];
        reinterpret_cast<float4*>(out)[base + tid] = xo;
        out[(size_t)B * 4 + base + tid] = ldacc[tid];
    }
}

extern "C" void kernel_launch(void* const* d_in, const int* in_sizes, int n_in,
                              void* d_out, int out_size, void* d_ws, size_t ws_size,
                              hipStream_t stream) {
    const float* inp  = (const float*)d_in[0];
    const float* cond = (const float*)d_in[1];
    const float* W1   = (const float*)d_in[2];
    const float* b1   = (const float*)d_in[3];
    const float* W2   = (const float*)d_in[4];
    const float* b2   = (const float*)d_in[5];
    const float* W3   = (const float*)d_in[6];
    const float* b3   = (const float*)d_in[7];
    float* out = (float*)d_out;
    int B = in_sizes[0] / 4;

    float* W2P = (float*)d_ws;                       // 262144 B
    float* W3P = (float*)((char*)d_ws + 262144);     // 98304 B
    float* W1S = (float*)((char*)d_ws + 360448);     // 8192 B

    hipLaunchKernelGGL(prep_v7, dim3(360), dim3(256), 0, stream,
                       W1, b1, W2, W3, W2P, W3P, W1S);
    hipLaunchKernelGGL(rqs_v7, dim3(B / 128), dim3(256), 0, stream,
                       inp, cond, W2P, W3P, W1S, b2, b3, out, B);
}